// Round 8
// baseline (2736.221 us; speedup 1.0000x reference)
//
#include <hip/hip_runtime.h>

#define HW 3136
#define NB 32
#define NC 128

__global__ __launch_bounds__(256, 4)
void mvg_kernel(const float* __restrict__ emb, float* __restrict__ out) {
  // XCD-bijective swizzle (3136 = 8*392): contiguous pos chunk per XCD.
  const int bid = blockIdx.x;
  const int pos = (bid & 7) * 392 + (bid >> 3);
  const int t = threadIdx.x;
  const int rm = t >> 4;
  const int cm = t & 15;
  const int i0 = rm << 3;
  const int c0 = cm << 3;

  __shared__ float Xs[NB * NC];                    // dense 16 KB slice
  __shared__ __align__(16) float hbuf[2][132];     // encoded pivot row h
  __shared__ __align__(16) float gbuf[2][132];     // pre-scaled row g = h/d
  __shared__ float ms[NC];

  // ---- gather the (B, C) slice ----
  #pragma unroll
  for (int m = 0; m < 16; ++m) {
    const int idx = t + 256 * m;
    const int b = idx >> 7;
    const int c = idx & (NC - 1);
    Xs[idx] = emb[(size_t)b * ((size_t)NC * HW) + (size_t)c * HW + pos];
  }
  __syncthreads();

  // ---- mean over batch, write mean output ----
  if (t < NC) {
    float s = 0.f;
    #pragma unroll
    for (int b = 0; b < NB; ++b) s += Xs[b * NC + t];
    const float m = s * (1.0f / NB);
    ms[t] = m;
    out[(size_t)t * HW + pos] = m;
  }
  __syncthreads();

  // ---- center ----
  #pragma unroll
  for (int m = 0; m < 16; ++m) {
    const int idx = t + 256 * m;
    Xs[idx] -= ms[idx & (NC - 1)];
  }
  __syncthreads();

  float4 a0[8], a1[8];
  #pragma unroll
  for (int r = 0; r < 8; ++r) {
    a0[r] = make_float4(0.f, 0.f, 0.f, 0.f);
    a1[r] = make_float4(0.f, 0.f, 0.f, 0.f);
  }

  // ---- covariance accumulate ----
  for (int b = 0; b < NB; ++b) {
    const float* xr = &Xs[b * NC];
    const float4 rv0 = *(const float4*)&xr[c0];
    const float4 rv1 = *(const float4*)&xr[c0 + 4];
    const float4 cv0 = *(const float4*)&xr[i0];
    const float4 cv1 = *(const float4*)&xr[i0 + 4];
    const float cr[8] = {cv0.x, cv0.y, cv0.z, cv0.w, cv1.x, cv1.y, cv1.z, cv1.w};
    #pragma unroll
    for (int r = 0; r < 8; ++r) {
      a0[r].x = fmaf(cr[r], rv0.x, a0[r].x);
      a0[r].y = fmaf(cr[r], rv0.y, a0[r].y);
      a0[r].z = fmaf(cr[r], rv0.z, a0[r].z);
      a0[r].w = fmaf(cr[r], rv0.w, a0[r].w);
      a1[r].x = fmaf(cr[r], rv1.x, a1[r].x);
      a1[r].y = fmaf(cr[r], rv1.y, a1[r].y);
      a1[r].z = fmaf(cr[r], rv1.z, a1[r].z);
      a1[r].w = fmaf(cr[r], rv1.w, a1[r].w);
    }
  }

  // ---- scale 1/(B-1), + (REG_DIAG+REG_EPS) I ----
  {
    const float s31 = 1.0f / (float)(NB - 1);
    const float RD = 0.01f + 1e-5f;
    #pragma unroll
    for (int r = 0; r < 8; ++r) {
      const int gr = i0 + r;
      a0[r].x = a0[r].x * s31 + ((gr == c0 + 0) ? RD : 0.f);
      a0[r].y = a0[r].y * s31 + ((gr == c0 + 1) ? RD : 0.f);
      a0[r].z = a0[r].z * s31 + ((gr == c0 + 2) ? RD : 0.f);
      a0[r].w = a0[r].w * s31 + ((gr == c0 + 3) ? RD : 0.f);
      a1[r].x = a1[r].x * s31 + ((gr == c0 + 4) ? RD : 0.f);
      a1[r].y = a1[r].y * s31 + ((gr == c0 + 5) ? RD : 0.f);
      a1[r].z = a1[r].z * s31 + ((gr == c0 + 6) ? RD : 0.f);
      a1[r].w = a1[r].w * s31 + ((gr == c0 + 7) ? RD : 0.f);
    }
  }

  // ---- prologue: publish h_0 = row0 - e0 (slot 0 = d-1), g_0 = h_0/d0 ----
  if (rm == 0) {
    const float d0 = __shfl(a0[0].x, 0, 16);     // raw diagonal from lane cm=0
    const float rd0 = __builtin_amdgcn_rcpf(d0);
    float4 t0 = a0[0], t1 = a1[0];
    if (cm == 0) t0.x -= 1.0f;
    *(float4*)&hbuf[0][c0] = t0;
    *(float4*)&hbuf[0][c0 + 4] = t1;
    float4 g0, g1;
    g0.x = t0.x * rd0; g0.y = t0.y * rd0; g0.z = t0.z * rd0; g0.w = t0.w * rd0;
    g1.x = t1.x * rd0; g1.y = t1.y * rd0; g1.z = t1.z * rd0; g1.w = t1.w * rd0;
    *(float4*)&gbuf[0][c0] = g0;
    *(float4*)&gbuf[0][c0 + 4] = g1;
  }
  __syncthreads();

  // STEP(P): pivot P's (h,g) live in buf[CUR]. All threads read their h-row
  // slice (c0) and g-col slice (i0) IN-STEP (data is stable: written before
  // the PREVIOUS barrier). Owner group (rm==OWNRM) computes row kk = P+1
  // updated by pivot P (coefficient cok = -g_P[kk], a compile-time-offset
  // scalar read), applies the h-encoding (-1 at static component), gets the
  // new diag via static-lane shfl, rcp once, publishes h and g = h*rd.
  // Barrier. Bulk: a[r] -= g_P[i0+r] * h_P  (exact R1 arithmetic).
  // Nothing lives across a barrier except the accumulators.
  #define STEP(P, CUR, NXT, OWNRM, LR, TR, TC) {                            \
    const float4 hr0 = *(const float4*)&hbuf[CUR][c0];                      \
    const float4 hr1 = *(const float4*)&hbuf[CUR][c0 + 4];                  \
    const float4 gc0 = *(const float4*)&gbuf[CUR][i0];                      \
    const float4 gc1 = *(const float4*)&gbuf[CUR][i0 + 4];                  \
    if (rm == (OWNRM)) {                                                    \
      const float cok = -gbuf[CUR][(P) + 1];                                \
      float4 t0, t1;                                                        \
      t0.x = fmaf(cok, hr0.x, a0[LR].x);                                    \
      t0.y = fmaf(cok, hr0.y, a0[LR].y);                                    \
      t0.z = fmaf(cok, hr0.z, a0[LR].z);                                    \
      t0.w = fmaf(cok, hr0.w, a0[LR].w);                                    \
      t1.x = fmaf(cok, hr1.x, a1[LR].x);                                    \
      t1.y = fmaf(cok, hr1.y, a1[LR].y);                                    \
      t1.z = fmaf(cok, hr1.z, a1[LR].z);                                    \
      t1.w = fmaf(cok, hr1.w, a1[LR].w);                                    \
      if (cm == (OWNRM)) TR.TC -= 1.0f;                                     \
      const float tde = __shfl(TR.TC, (OWNRM), 16);                         \
      const float rd = __builtin_amdgcn_rcpf(tde + 1.0f);                   \
      float4 g0, g1;                                                        \
      g0.x = t0.x * rd; g0.y = t0.y * rd;                                   \
      g0.z = t0.z * rd; g0.w = t0.w * rd;                                   \
      g1.x = t1.x * rd; g1.y = t1.y * rd;                                   \
      g1.z = t1.z * rd; g1.w = t1.w * rd;                                   \
      *(float4*)&hbuf[NXT][c0] = t0;                                        \
      *(float4*)&hbuf[NXT][c0 + 4] = t1;                                    \
      *(float4*)&gbuf[NXT][c0] = g0;                                        \
      *(float4*)&gbuf[NXT][c0 + 4] = g1;                                    \
    }                                                                       \
    __syncthreads();                                                        \
    {                                                                       \
      const float cr[8] = {gc0.x, gc0.y, gc0.z, gc0.w,                      \
                           gc1.x, gc1.y, gc1.z, gc1.w};                     \
      _Pragma("unroll")                                                     \
      for (int r = 0; r < 8; ++r) {                                         \
        a0[r].x = fmaf(-cr[r], hr0.x, a0[r].x);                             \
        a0[r].y = fmaf(-cr[r], hr0.y, a0[r].y);                             \
        a0[r].z = fmaf(-cr[r], hr0.z, a0[r].z);                             \
        a0[r].w = fmaf(-cr[r], hr0.w, a0[r].w);                             \
        a1[r].x = fmaf(-cr[r], hr1.x, a1[r].x);                             \
        a1[r].y = fmaf(-cr[r], hr1.y, a1[r].y);                             \
        a1[r].z = fmaf(-cr[r], hr1.z, a1[r].z);                             \
        a1[r].w = fmaf(-cr[r], hr1.w, a1[r].w);                             \
      }                                                                     \
    }                                                                       \
  }

  // ---- 128 pivots: 16 iterations x 8 static steps ----
  #pragma unroll 1
  for (int q = 0; q < 16; ++q) {
    STEP(8 * q + 0, 0, 1, q,     1, t0, y)
    STEP(8 * q + 1, 1, 0, q,     2, t0, z)
    STEP(8 * q + 2, 0, 1, q,     3, t0, w)
    STEP(8 * q + 3, 1, 0, q,     4, t1, x)
    STEP(8 * q + 4, 0, 1, q,     5, t1, y)
    STEP(8 * q + 5, 1, 0, q,     6, t1, z)
    STEP(8 * q + 6, 0, 1, q,     7, t1, w)
    STEP(8 * q + 7, 1, 0, q + 1, 0, t0, x)   // q=15: OWNRM=16 -> publish dead
  }

  // ---- store: inv = -reg, diag = 2 - reg (undo the +2 encoding artifact) ----
  float* o = out + (size_t)NC * HW + (size_t)pos * (NC * NC);
  #pragma unroll
  for (int r = 0; r < 8; ++r) {
    const int gr = i0 + r;
    float4 w0, w1;
    w0.x = (gr == c0 + 0) ? (2.0f - a0[r].x) : (-a0[r].x);
    w0.y = (gr == c0 + 1) ? (2.0f - a0[r].y) : (-a0[r].y);
    w0.z = (gr == c0 + 2) ? (2.0f - a0[r].z) : (-a0[r].z);
    w0.w = (gr == c0 + 3) ? (2.0f - a0[r].w) : (-a0[r].w);
    w1.x = (gr == c0 + 4) ? (2.0f - a1[r].x) : (-a1[r].x);
    w1.y = (gr == c0 + 5) ? (2.0f - a1[r].y) : (-a1[r].y);
    w1.z = (gr == c0 + 6) ? (2.0f - a1[r].z) : (-a1[r].z);
    w1.w = (gr == c0 + 7) ? (2.0f - a1[r].w) : (-a1[r].w);
    *(float4*)&o[(size_t)gr * NC + c0] = w0;
    *(float4*)&o[(size_t)gr * NC + c0 + 4] = w1;
  }
}

extern "C" void kernel_launch(void* const* d_in, const int* in_sizes, int n_in,
                              void* d_out, int out_size, void* d_ws, size_t ws_size,
                              hipStream_t stream) {
  const float* emb = (const float*)d_in[0];
  float* out = (float*)d_out;
  mvg_kernel<<<HW, 256, 0, stream>>>(emb, out);
}

// Round 9
// 279.559 us; speedup vs baseline: 9.7876x; 9.7876x over previous
//
#include <hip/hip_runtime.h>

#define HW 3136
#define NB 32
#define NC 128

// 512 threads: thread owns an 8-row x 4-col tile. rm = t>>5 (16 row tiles),
// cm = t&31 (32 col tiles). Rank-2 sweep steps (pivots k,k+1), 64 barriers.
__global__ __launch_bounds__(512, 4)
void mvg_kernel(const float* __restrict__ emb, float* __restrict__ out) {
  // XCD-bijective swizzle (3136 = 8*392): contiguous pos chunk per XCD.
  const int bid = blockIdx.x;
  const int pos = (bid & 7) * 392 + (bid >> 3);
  const int t = threadIdx.x;
  const int rm = t >> 5;
  const int cm = t & 31;
  const int i0 = rm << 3;
  const int c0 = cm << 2;

  __shared__ float Xs[NB * NC];                    // dense 16 KB slice
  __shared__ __align__(16) float Hb[2][2][132];    // h rows, [parity][j][.]
  __shared__ __align__(16) float Gb[2][2][132];    // g rows = h/d
  __shared__ float ms[NC];

  // ---- gather the (B, C) slice ----
  #pragma unroll
  for (int m = 0; m < 8; ++m) {
    const int idx = t + 512 * m;
    const int b = idx >> 7;
    const int c = idx & (NC - 1);
    Xs[idx] = emb[(size_t)b * (size_t)(NC * HW) + (size_t)c * HW + pos];
  }
  __syncthreads();

  // ---- mean over batch, write mean output ----
  if (t < NC) {
    float s = 0.f;
    #pragma unroll
    for (int b = 0; b < NB; ++b) s += Xs[b * NC + t];
    const float m = s * (1.0f / NB);
    ms[t] = m;
    out[(size_t)t * HW + pos] = m;
  }
  __syncthreads();

  // ---- center ----
  #pragma unroll
  for (int m = 0; m < 8; ++m) {
    const int idx = t + 512 * m;
    Xs[idx] -= ms[idx & (NC - 1)];
  }
  __syncthreads();

  float4 a[8];
  #pragma unroll
  for (int r = 0; r < 8; ++r) a[r] = make_float4(0.f, 0.f, 0.f, 0.f);

  // ---- covariance accumulate (rv: 2-lane broadcast; cv: 32-lane broadcast) ----
  for (int b = 0; b < NB; ++b) {
    const float* xr = &Xs[b * NC];
    const float4 rv  = *(const float4*)&xr[c0];
    const float4 cv0 = *(const float4*)&xr[i0];
    const float4 cv1 = *(const float4*)&xr[i0 + 4];
    const float cr[8] = {cv0.x, cv0.y, cv0.z, cv0.w, cv1.x, cv1.y, cv1.z, cv1.w};
    #pragma unroll
    for (int r = 0; r < 8; ++r) {
      a[r].x = fmaf(cr[r], rv.x, a[r].x);
      a[r].y = fmaf(cr[r], rv.y, a[r].y);
      a[r].z = fmaf(cr[r], rv.z, a[r].z);
      a[r].w = fmaf(cr[r], rv.w, a[r].w);
    }
  }

  // ---- scale 1/(B-1), + (REG_DIAG+REG_EPS) I ----
  {
    const float s31 = 1.0f / (float)(NB - 1);
    const float RD = 0.01f + 1e-5f;
    #pragma unroll
    for (int r = 0; r < 8; ++r) {
      const int gr = i0 + r;
      a[r].x = a[r].x * s31 + ((gr == c0 + 0) ? RD : 0.f);
      a[r].y = a[r].y * s31 + ((gr == c0 + 1) ? RD : 0.f);
      a[r].z = a[r].z * s31 + ((gr == c0 + 2) ? RD : 0.f);
      a[r].w = a[r].w * s31 + ((gr == c0 + 3) ? RD : 0.f);
    }
  }

  // PAIR(Q,J,PB,CK,CK1,JH): pivots k=8Q+2J, k+1. Owner group (rm==Q):
  //   h_k   = a[2J] - e_k            (current through k-1: prev bulk done)
  //   d     = h_k[k] + 1, g_k = h_k * rcp(d)
  //   h_k+1 = a[2J+1] - g_k[k+1]*h_k - e_{k+1}
  //   d'    = h_k+1[k+1] + 1, g_k+1 = h_k+1 * rcp(d')
  //   publish all four rows (thread's 4-col slices), BARRIER, then everyone:
  //   a[r] -= g_k[i0+r]*h_k + g_k+1[i0+r]*h_k+1   (h-encoding covers rows k,k+1)
  // Col k sits at thread cmd = 2Q+JH, component CK; col k+1: same thread, CK1.
  #define PAIR(Q, J, PB, CK, CK1, JH) {                                     \
    if (rm == (Q)) {                                                        \
      const int cmd = 2 * (Q) + (JH);                                       \
      float4 hk = a[2 * (J)];                                               \
      if (cm == cmd) hk.CK -= 1.0f;                                         \
      const float d0 = __shfl(hk.CK, cmd, 32) + 1.0f;                       \
      const float rd0 = __builtin_amdgcn_rcpf(d0);                          \
      float4 gk;                                                            \
      gk.x = hk.x * rd0; gk.y = hk.y * rd0;                                 \
      gk.z = hk.z * rd0; gk.w = hk.w * rd0;                                 \
      const float ck1 = __shfl(gk.CK1, cmd, 32);                            \
      float4 hs;                                                            \
      hs.x = fmaf(-ck1, hk.x, a[2 * (J) + 1].x);                            \
      hs.y = fmaf(-ck1, hk.y, a[2 * (J) + 1].y);                            \
      hs.z = fmaf(-ck1, hk.z, a[2 * (J) + 1].z);                            \
      hs.w = fmaf(-ck1, hk.w, a[2 * (J) + 1].w);                            \
      if (cm == cmd) hs.CK1 -= 1.0f;                                        \
      const float d1 = __shfl(hs.CK1, cmd, 32) + 1.0f;                      \
      const float rd1 = __builtin_amdgcn_rcpf(d1);                          \
      float4 gs;                                                            \
      gs.x = hs.x * rd1; gs.y = hs.y * rd1;                                 \
      gs.z = hs.z * rd1; gs.w = hs.w * rd1;                                 \
      *(float4*)&Hb[PB][0][c0] = hk;                                        \
      *(float4*)&Hb[PB][1][c0] = hs;                                        \
      *(float4*)&Gb[PB][0][c0] = gk;                                        \
      *(float4*)&Gb[PB][1][c0] = gs;                                        \
    }                                                                       \
    __syncthreads();                                                        \
    {                                                                       \
      const float4 hr  = *(const float4*)&Hb[PB][0][c0];                    \
      const float4 hs_ = *(const float4*)&Hb[PB][1][c0];                    \
      const float4 gA0 = *(const float4*)&Gb[PB][0][i0];                    \
      const float4 gA1 = *(const float4*)&Gb[PB][0][i0 + 4];                \
      const float4 gB0 = *(const float4*)&Gb[PB][1][i0];                    \
      const float4 gB1 = *(const float4*)&Gb[PB][1][i0 + 4];                \
      const float cA[8] = {gA0.x, gA0.y, gA0.z, gA0.w,                      \
                           gA1.x, gA1.y, gA1.z, gA1.w};                     \
      const float cB[8] = {gB0.x, gB0.y, gB0.z, gB0.w,                      \
                           gB1.x, gB1.y, gB1.z, gB1.w};                     \
      _Pragma("unroll")                                                     \
      for (int r = 0; r < 8; ++r) {                                         \
        a[r].x = fmaf(-cA[r], hr.x, fmaf(-cB[r], hs_.x, a[r].x));           \
        a[r].y = fmaf(-cA[r], hr.y, fmaf(-cB[r], hs_.y, a[r].y));           \
        a[r].z = fmaf(-cA[r], hr.z, fmaf(-cB[r], hs_.z, a[r].z));           \
        a[r].w = fmaf(-cA[r], hr.w, fmaf(-cB[r], hs_.w, a[r].w));           \
      }                                                                     \
    }                                                                       \
  }

  // ---- 64 rank-2 steps: 16 iterations x 4 static pairs ----
  #pragma unroll 1
  for (int q = 0; q < 16; ++q) {
    PAIR(q, 0, 0, x, y, 0)    // k = 8q+0: comp x / y, cmd = 2q
    PAIR(q, 1, 1, z, w, 0)    // k = 8q+2: comp z / w, cmd = 2q
    PAIR(q, 2, 0, x, y, 1)    // k = 8q+4: comp x / y, cmd = 2q+1
    PAIR(q, 3, 1, z, w, 1)    // k = 8q+6: comp z / w, cmd = 2q+1
  }

  // ---- store: inv = -a, diag = 2 - a (undo the +2 encoding artifact) ----
  float* o = out + (size_t)NC * HW + (size_t)pos * (NC * NC);
  #pragma unroll
  for (int r = 0; r < 8; ++r) {
    const int gr = i0 + r;
    float4 w;
    w.x = (gr == c0 + 0) ? (2.0f - a[r].x) : (-a[r].x);
    w.y = (gr == c0 + 1) ? (2.0f - a[r].y) : (-a[r].y);
    w.z = (gr == c0 + 2) ? (2.0f - a[r].z) : (-a[r].z);
    w.w = (gr == c0 + 3) ? (2.0f - a[r].w) : (-a[r].w);
    *(float4*)&o[(size_t)gr * NC + c0] = w;
  }
}

extern "C" void kernel_launch(void* const* d_in, const int* in_sizes, int n_in,
                              void* d_out, int out_size, void* d_ws, size_t ws_size,
                              hipStream_t stream) {
  const float* emb = (const float*)d_in[0];
  float* out = (float*)d_out;
  mvg_kernel<<<HW, 512, 0, stream>>>(emb, out);
}